// Round 3
// baseline (155.859 us; speedup 1.0000x reference)
//
#include <hip/hip_runtime.h>

// CRF-RNN mean-field, fully fused into ONE persistent kernel.
// Grid 24(z) x 24(y) x 16(x), N=9216, C=2, 5 iterations.
//
// Ks (theta=3) = Gz (x) Gy (x) Gx  -- exact separable 1-D convs.
// Kb = S160 * E_i E_j * exp(I3_i*I3_j), Taylor NT=5 in intensity (err ~1e-7).
// 12 fields/iter: f0,f1 = q (theta=3); f(2+2t+c) = P_t*q_c (theta=160).
// 24 blocks (one per z-slice) x 384 threads (one per yx). q, u, norms live in
// registers across iterations. Grid barrier: per-phase device-scope counters
// (zeroed each call by init kernel -- ws is re-poisoned 0xAA every replay).

#define DD 24
#define HH 24
#define WW 16
#define SLICE 384
#define NPTS 9216
#define NT 5
#define TP 12            // tmp floats per point
#define NP 8             // tmpN floats per point (5 used)
#define LPITCH 196       // LDS row pitch in floats (16*12 + 4)
#define NBLOCKS 24
#define LOG2E 1.4426950408889634f
#define K3L   (LOG2E / 18.0f)
#define K160L (LOG2E / 51200.0f)

static __device__ __forceinline__ int iabs(int a) { return a < 0 ? -a : a; }

__global__ void init_bar_kernel(unsigned* bar) {
    if (threadIdx.x < 8) bar[threadIdx.x] = 0u;
}

static __device__ __forceinline__ void gridbar(unsigned* bar, int phase) {
    __syncthreads();
    if (threadIdx.x == 0) {
        __threadfence();  // release my global writes (device scope)
        __hip_atomic_fetch_add(&bar[phase], 1u, __ATOMIC_ACQ_REL,
                               __HIP_MEMORY_SCOPE_AGENT);
        while (__hip_atomic_load(&bar[phase], __ATOMIC_ACQUIRE,
                                 __HIP_MEMORY_SCOPE_AGENT) < (unsigned)NBLOCKS) {
            __builtin_amdgcn_s_sleep(1);
        }
        __threadfence();  // acquire others' writes
    }
    __syncthreads();
}

// xy separable conv of 12 staged fields; f0,f1 with g3, f2..11 with g160.
static __device__ __forceinline__ void xy_conv12(
        float* sA, float* sB, const float* g3, const float* g160,
        int y, int x, const float v[12], float ov[12]) {
    float4* wrow = (float4*)(sA + y * LPITCH + x * 12);
    wrow[0] = make_float4(v[0], v[1], v[2], v[3]);
    wrow[1] = make_float4(v[4], v[5], v[6], v[7]);
    wrow[2] = make_float4(v[8], v[9], v[10], v[11]);
    __syncthreads();

    float ax[12];
#pragma unroll
    for (int f = 0; f < 12; ++f) ax[f] = 0.f;
    const float4* rowy = (const float4*)(sA + y * LPITCH);
#pragma unroll
    for (int xp = 0; xp < WW; ++xp) {
        int d = iabs(x - xp);
        float w3 = g3[d], wb = g160[d];
        float4 a0 = rowy[xp * 3 + 0];
        float4 a1 = rowy[xp * 3 + 1];
        float4 a2 = rowy[xp * 3 + 2];
        ax[0] = fmaf(w3, a0.x, ax[0]);  ax[1] = fmaf(w3, a0.y, ax[1]);
        ax[2] = fmaf(wb, a0.z, ax[2]);  ax[3] = fmaf(wb, a0.w, ax[3]);
        ax[4] = fmaf(wb, a1.x, ax[4]);  ax[5] = fmaf(wb, a1.y, ax[5]);
        ax[6] = fmaf(wb, a1.z, ax[6]);  ax[7] = fmaf(wb, a1.w, ax[7]);
        ax[8] = fmaf(wb, a2.x, ax[8]);  ax[9] = fmaf(wb, a2.y, ax[9]);
        ax[10] = fmaf(wb, a2.z, ax[10]); ax[11] = fmaf(wb, a2.w, ax[11]);
    }
    float4* wrowB = (float4*)(sB + y * LPITCH + x * 12);
    wrowB[0] = make_float4(ax[0], ax[1], ax[2], ax[3]);
    wrowB[1] = make_float4(ax[4], ax[5], ax[6], ax[7]);
    wrowB[2] = make_float4(ax[8], ax[9], ax[10], ax[11]);
    __syncthreads();

#pragma unroll
    for (int f = 0; f < 12; ++f) ov[f] = 0.f;
#pragma unroll
    for (int yp = 0; yp < HH; ++yp) {
        int d = iabs(y - yp);
        float w3 = g3[d], wb = g160[d];
        const float4* col = (const float4*)(sB + yp * LPITCH + x * 12);
        float4 b0 = col[0];
        float4 b1 = col[1];
        float4 b2 = col[2];
        ov[0] = fmaf(w3, b0.x, ov[0]);  ov[1] = fmaf(w3, b0.y, ov[1]);
        ov[2] = fmaf(wb, b0.z, ov[2]);  ov[3] = fmaf(wb, b0.w, ov[3]);
        ov[4] = fmaf(wb, b1.x, ov[4]);  ov[5] = fmaf(wb, b1.y, ov[5]);
        ov[6] = fmaf(wb, b1.z, ov[6]);  ov[7] = fmaf(wb, b1.w, ov[7]);
        ov[8] = fmaf(wb, b2.x, ov[8]);  ov[9] = fmaf(wb, b2.y, ov[9]);
        ov[10] = fmaf(wb, b2.z, ov[10]); ov[11] = fmaf(wb, b2.w, ov[11]);
    }
    __syncthreads();   // sA/sB reusable after this
}

__global__ __launch_bounds__(384, 1)
void crf_persist(const float2* __restrict__ u2, const float* __restrict__ rgb,
                 const float* __restrict__ sw, const float* __restrict__ bw,
                 const float* __restrict__ compat,
                 float* __restrict__ tmpA, float* __restrict__ tmpB,
                 float* __restrict__ tmpN, unsigned* __restrict__ bar,
                 float2* __restrict__ out) {
    __shared__ float g3[32];
    __shared__ float g160[32];
    __shared__ float sA[HH * LPITCH];
    __shared__ float sB[HH * LPITCH];

    const int z = blockIdx.x;
    const int t = threadIdx.x;
    const int y = t >> 4;
    const int x = t & 15;
    const int i = z * SLICE + t;

    if (t < DD) {
        g3[t] = exp2f(-(float)(t * t) * K3L);
        g160[t] = exp2f(-(float)(t * t) * K160L);
    }
    __syncthreads();

    // per-thread invariants (live in registers for the whole kernel)
    float sx = 0.f, sy = 0.f, sz = 0.f;
    for (int xp = 0; xp < WW; ++xp) sx += g3[iabs(x - xp)];
    for (int yp = 0; yp < HH; ++yp) sy += g3[iabs(y - yp)];
    for (int zp = 0; zp < DD; ++zp) sz += g3[iabs(z - zp)];
    const float inv_ns = 1.0f / (sx * sy * sz);
    const float I3 = rgb[i] * (1.0f / 3.0f);
    const float E = exp2f(-0.5f * LOG2E * I3 * I3);
    const float2 uu = u2[i];
    const float sw0 = sw[0], sw1 = sw[1];
    const float bw0 = bw[0], bw1 = bw[1];
    const float c00 = compat[0], c01 = compat[1];
    const float c10 = compat[2], c11 = compat[3];
    const float invf[NT] = {1.f, 1.f, 0.5f, 1.f / 6.f, 1.f / 24.f};
    float Pt[NT];
    Pt[0] = E;
#pragma unroll
    for (int k = 1; k < NT; ++k) Pt[k] = Pt[k - 1] * I3;

    float v[12], ov[12];

    // ---- P0: norm xy-filter + iter-1 xy-filter (q = u) ----
#pragma unroll
    for (int f = 0; f < 12; ++f) v[f] = 0.f;
#pragma unroll
    for (int k = 0; k < NT; ++k) v[2 + k] = Pt[k];
    xy_conv12(sA, sB, g3, g160, y, x, v, ov);
    {
        float* pn = tmpN + (size_t)i * NP;
        *(float4*)pn = make_float4(ov[2], ov[3], ov[4], ov[5]);
        pn[4] = ov[6];
    }
    float q0 = uu.x, q1 = uu.y;
    v[0] = q0; v[1] = q1;
#pragma unroll
    for (int k = 0; k < NT; ++k) { v[2 + 2 * k] = Pt[k] * q0; v[3 + 2 * k] = Pt[k] * q1; }
    xy_conv12(sA, sB, g3, g160, y, x, v, ov);
    {
        float4* pd = (float4*)(tmpA + (size_t)i * TP);
        pd[0] = make_float4(ov[0], ov[1], ov[2], ov[3]);
        pd[1] = make_float4(ov[4], ov[5], ov[6], ov[7]);
        pd[2] = make_float4(ov[8], ov[9], ov[10], ov[11]);
    }
    gridbar(bar, 0);

    float inv_nb = 0.f;
    const float* tsrc = tmpA;
    float* tdst = tmpB;

    for (int it = 0; it < 5; ++it) {
        if (it == 0) {
            // norm_b z-conv (once; result kept in a register)
            float accN[NT] = {0.f, 0.f, 0.f, 0.f, 0.f};
            const float* pn = tmpN + (size_t)t * NP;
            for (int zp = 0; zp < DD; ++zp) {
                float wb = g160[iabs(z - zp)];
                float4 n0 = *(const float4*)pn;
                float n4 = pn[4];
                accN[0] = fmaf(wb, n0.x, accN[0]);
                accN[1] = fmaf(wb, n0.y, accN[1]);
                accN[2] = fmaf(wb, n0.z, accN[2]);
                accN[3] = fmaf(wb, n0.w, accN[3]);
                accN[4] = fmaf(wb, n4, accN[4]);
                pn += (size_t)SLICE * NP;
            }
            float nb = 0.f;
#pragma unroll
            for (int k = 0; k < NT; ++k) nb = fmaf(Pt[k] * invf[k], accN[k], nb);
            inv_nb = 1.0f / nb;
        }

        // z-conv of 12 fields
        float acc[12];
#pragma unroll
        for (int f = 0; f < 12; ++f) acc[f] = 0.f;
        {
            const float* p = tsrc + (size_t)t * TP;
            for (int zp = 0; zp < DD; ++zp) {
                int d = iabs(z - zp);
                float w3 = g3[d], wb = g160[d];
                float4 a0 = ((const float4*)p)[0];
                float4 a1 = ((const float4*)p)[1];
                float4 a2 = ((const float4*)p)[2];
                acc[0] = fmaf(w3, a0.x, acc[0]);  acc[1] = fmaf(w3, a0.y, acc[1]);
                acc[2] = fmaf(wb, a0.z, acc[2]);  acc[3] = fmaf(wb, a0.w, acc[3]);
                acc[4] = fmaf(wb, a1.x, acc[4]);  acc[5] = fmaf(wb, a1.y, acc[5]);
                acc[6] = fmaf(wb, a1.z, acc[6]);  acc[7] = fmaf(wb, a1.w, acc[7]);
                acc[8] = fmaf(wb, a2.x, acc[8]);  acc[9] = fmaf(wb, a2.y, acc[9]);
                acc[10] = fmaf(wb, a2.z, acc[10]); acc[11] = fmaf(wb, a2.w, acc[11]);
                p += (size_t)SLICE * TP;
            }
        }

        // mean-field update
        float s0 = acc[0] * inv_ns;
        float s1 = acc[1] * inv_ns;
        float b0 = 0.f, b1 = 0.f;
#pragma unroll
        for (int k = 0; k < NT; ++k) {
            float w = Pt[k] * invf[k];
            b0 = fmaf(w, acc[2 + 2 * k], b0);
            b1 = fmaf(w, acc[3 + 2 * k], b1);
        }
        b0 *= inv_nb;
        b1 *= inv_nb;
        float m0 = s0 * sw0 + b0 * bw0;
        float m1 = s1 * sw1 + b1 * bw1;
        float p0 = fmaf(c00, m0, c01 * m1);
        float p1 = fmaf(c10, m0, c11 * m1);
        q0 = uu.x - p0;
        q1 = uu.y - p1;

        if (it == 4) {
            out[i] = make_float2(q0, q1);
            break;
        }

        // xy-filter the new q for the next iteration
        v[0] = q0; v[1] = q1;
#pragma unroll
        for (int k = 0; k < NT; ++k) { v[2 + 2 * k] = Pt[k] * q0; v[3 + 2 * k] = Pt[k] * q1; }
        xy_conv12(sA, sB, g3, g160, y, x, v, ov);
        {
            float4* pd = (float4*)(tdst + (size_t)i * TP);
            pd[0] = make_float4(ov[0], ov[1], ov[2], ov[3]);
            pd[1] = make_float4(ov[4], ov[5], ov[6], ov[7]);
            pd[2] = make_float4(ov[8], ov[9], ov[10], ov[11]);
        }
        gridbar(bar, 1 + it);

        const float* ns = tdst;
        tdst = (float*)tsrc;
        tsrc = ns;
    }
}

extern "C" void kernel_launch(void* const* d_in, const int* in_sizes, int n_in,
                              void* d_out, int out_size, void* d_ws, size_t ws_size,
                              hipStream_t stream) {
    const float2* u2     = (const float2*)d_in[0];  // N*2
    const float*  rgb    = (const float*)d_in[1];   // N
    const float*  sw     = (const float*)d_in[2];
    const float*  bw     = (const float*)d_in[3];
    const float*  compat = (const float*)d_in[4];
    float2* out = (float2*)d_out;

    float* ws = (float*)d_ws;
    float* tmpA = ws;                          // NPTS*TP
    float* tmpB = ws + NPTS * TP;              // NPTS*TP
    float* tmpN = ws + 2 * NPTS * TP;          // NPTS*NP
    unsigned* bar = (unsigned*)(ws + 2 * NPTS * TP + NPTS * NP);  // 8 uints

    init_bar_kernel<<<1, 64, 0, stream>>>(bar);
    crf_persist<<<NBLOCKS, 384, 0, stream>>>(u2, rgb, sw, bw, compat,
                                             tmpA, tmpB, tmpN, bar, out);
}

// Round 4
// 120.427 us; speedup vs baseline: 1.2942x; 1.2942x over previous
//
#include <hip/hip_runtime.h>

// CRF-RNN mean-field, separable filters, ONE kernel per iteration.
// Grid 24(z) x 24(y) x 16(x), N=9216, C=2, 5 iterations.
//
// Ks (theta=3) = Gz (x) Gy (x) Gx  -- exact separable 1-D convs.
// Kb = S160 * E_i E_j * exp(I3_i*I3_j), Taylor NT=5 in intensity (err ~1e-7).
// 12 fields/iter: f0,f1 = q (theta=3); f(2+2t+c) = P_t*q_c (theta=160).
// Per-iteration kernel: z-conv(prev tmp) -> update -> xy-conv(new q) -> tmp.
// Block = one z-slice (384 threads, 1 pt/thread): the xy-conv only needs new
// q within the block's own slice, so stream order is the only sync needed.
// Lesson from R3: hand-rolled cross-XCD barriers force bulk L2 wb/inv
// (~19 us/iter); kernel-boundary coherence is far cheaper.

#define DD 24
#define HH 24
#define WW 16
#define SLICE 384
#define NPTS 9216
#define NT 5
#define TP 12            // tmp floats per point
#define LPITCH 196       // LDS row pitch in floats (16*12 + 4)
#define LOG2E 1.4426950408889634f
#define K3L   (LOG2E / 18.0f)
#define K160L (LOG2E / 51200.0f)

static __device__ __forceinline__ int iabs(int a) { return a < 0 ? -a : a; }

// xy separable conv of 12 staged fields; f0,f1 with g3, f2..11 with g160.
static __device__ __forceinline__ void xy_conv12(
        float* sA, float* sB, const float* g3, const float* g160,
        int y, int x, const float v[12], float ov[12]) {
    float4* wrow = (float4*)(sA + y * LPITCH + x * 12);
    wrow[0] = make_float4(v[0], v[1], v[2], v[3]);
    wrow[1] = make_float4(v[4], v[5], v[6], v[7]);
    wrow[2] = make_float4(v[8], v[9], v[10], v[11]);
    __syncthreads();

    float ax[12];
#pragma unroll
    for (int f = 0; f < 12; ++f) ax[f] = 0.f;
    const float4* rowy = (const float4*)(sA + y * LPITCH);
#pragma unroll
    for (int xp = 0; xp < WW; ++xp) {
        int d = iabs(x - xp);
        float w3 = g3[d], wb = g160[d];
        float4 a0 = rowy[xp * 3 + 0];
        float4 a1 = rowy[xp * 3 + 1];
        float4 a2 = rowy[xp * 3 + 2];
        ax[0] = fmaf(w3, a0.x, ax[0]);  ax[1] = fmaf(w3, a0.y, ax[1]);
        ax[2] = fmaf(wb, a0.z, ax[2]);  ax[3] = fmaf(wb, a0.w, ax[3]);
        ax[4] = fmaf(wb, a1.x, ax[4]);  ax[5] = fmaf(wb, a1.y, ax[5]);
        ax[6] = fmaf(wb, a1.z, ax[6]);  ax[7] = fmaf(wb, a1.w, ax[7]);
        ax[8] = fmaf(wb, a2.x, ax[8]);  ax[9] = fmaf(wb, a2.y, ax[9]);
        ax[10] = fmaf(wb, a2.z, ax[10]); ax[11] = fmaf(wb, a2.w, ax[11]);
    }
    __syncthreads();   // sA reusable; also orders sB writes below
    float4* wrowB = (float4*)(sB + y * LPITCH + x * 12);
    wrowB[0] = make_float4(ax[0], ax[1], ax[2], ax[3]);
    wrowB[1] = make_float4(ax[4], ax[5], ax[6], ax[7]);
    wrowB[2] = make_float4(ax[8], ax[9], ax[10], ax[11]);
    __syncthreads();

#pragma unroll
    for (int f = 0; f < 12; ++f) ov[f] = 0.f;
#pragma unroll
    for (int yp = 0; yp < HH; ++yp) {
        int d = iabs(y - yp);
        float w3 = g3[d], wb = g160[d];
        const float4* col = (const float4*)(sB + yp * LPITCH + x * 12);
        float4 b0 = col[0];
        float4 b1 = col[1];
        float4 b2 = col[2];
        ov[0] = fmaf(w3, b0.x, ov[0]);  ov[1] = fmaf(w3, b0.y, ov[1]);
        ov[2] = fmaf(wb, b0.z, ov[2]);  ov[3] = fmaf(wb, b0.w, ov[3]);
        ov[4] = fmaf(wb, b1.x, ov[4]);  ov[5] = fmaf(wb, b1.y, ov[5]);
        ov[6] = fmaf(wb, b1.z, ov[6]);  ov[7] = fmaf(wb, b1.w, ov[7]);
        ov[8] = fmaf(wb, b2.x, ov[8]);  ov[9] = fmaf(wb, b2.y, ov[9]);
        ov[10] = fmaf(wb, b2.z, ov[10]); ov[11] = fmaf(wb, b2.w, ov[11]);
    }
    __syncthreads();   // sA/sB reusable after this
}

static __device__ __forceinline__ void write12(float* dst, const float ov[12]) {
    float4* pd = (float4*)dst;
    pd[0] = make_float4(ov[0], ov[1], ov[2], ov[3]);
    pd[1] = make_float4(ov[4], ov[5], ov[6], ov[7]);
    pd[2] = make_float4(ov[8], ov[9], ov[10], ov[11]);
}

// ---- precompute: xy-filter of iter-1 fields (q=u) and norm fields (P_t) ----
__global__ __launch_bounds__(SLICE)
void crf_pre(const float2* __restrict__ u2, const float* __restrict__ rgb,
             float* __restrict__ tmpA, float* __restrict__ tmpN) {
    __shared__ float g3[32];
    __shared__ float g160[32];
    __shared__ float sA[HH * LPITCH];
    __shared__ float sB[HH * LPITCH];
    const int z = blockIdx.x;
    const int t = threadIdx.x;
    const int y = t >> 4, x = t & 15;
    const int i = z * SLICE + t;

    if (t < DD) {
        g3[t] = exp2f(-(float)(t * t) * K3L);
        g160[t] = exp2f(-(float)(t * t) * K160L);
    }
    __syncthreads();

    const float I3 = rgb[i] * (1.0f / 3.0f);
    const float E = exp2f(-0.5f * LOG2E * I3 * I3);
    float Pt[NT];
    Pt[0] = E;
#pragma unroll
    for (int k = 1; k < NT; ++k) Pt[k] = Pt[k - 1] * I3;
    const float2 uu = u2[i];

    float v[12], ov[12];
    // norm fields: P_t at slots 2..6 (g160 path), rest zero
#pragma unroll
    for (int f = 0; f < 12; ++f) v[f] = 0.f;
#pragma unroll
    for (int k = 0; k < NT; ++k) v[2 + k] = Pt[k];
    xy_conv12(sA, sB, g3, g160, y, x, v, ov);
    write12(tmpN + (size_t)i * TP, ov);

    // iter-1 fields with q = u
    v[0] = uu.x; v[1] = uu.y;
#pragma unroll
    for (int k = 0; k < NT; ++k) { v[2 + 2 * k] = Pt[k] * uu.x; v[3 + 2 * k] = Pt[k] * uu.y; }
    xy_conv12(sA, sB, g3, g160, y, x, v, ov);
    write12(tmpA + (size_t)i * TP, ov);
}

// ---- one mean-field iteration: z-conv + update + xy-conv -------------------
__global__ __launch_bounds__(SLICE)
void crf_iter(const float* __restrict__ tsrc, float* __restrict__ tdst,
              const float* __restrict__ tmpN, float* __restrict__ normb,
              const float* __restrict__ rgb, const float2* __restrict__ u2,
              const float* __restrict__ sw, const float* __restrict__ bw,
              const float* __restrict__ compat,
              float2* __restrict__ out, int it) {
    __shared__ float g3[32];
    __shared__ float g160[32];
    __shared__ float sA[HH * LPITCH];
    __shared__ float sB[HH * LPITCH];
    const int z = blockIdx.x;
    const int t = threadIdx.x;
    const int y = t >> 4, x = t & 15;
    const int i = z * SLICE + t;

    if (t < DD) {
        g3[t] = exp2f(-(float)(t * t) * K3L);
        g160[t] = exp2f(-(float)(t * t) * K160L);
    }
    __syncthreads();

    // z-conv of 12 fields (issue loads early; everything below overlaps)
    float acc[12];
#pragma unroll
    for (int f = 0; f < 12; ++f) acc[f] = 0.f;
    {
        const float* p = tsrc + (size_t)t * TP;
#pragma unroll 4
        for (int zp = 0; zp < DD; ++zp) {
            int d = iabs(z - zp);
            float w3 = g3[d], wb = g160[d];
            float4 a0 = ((const float4*)p)[0];
            float4 a1 = ((const float4*)p)[1];
            float4 a2 = ((const float4*)p)[2];
            acc[0] = fmaf(w3, a0.x, acc[0]);  acc[1] = fmaf(w3, a0.y, acc[1]);
            acc[2] = fmaf(wb, a0.z, acc[2]);  acc[3] = fmaf(wb, a0.w, acc[3]);
            acc[4] = fmaf(wb, a1.x, acc[4]);  acc[5] = fmaf(wb, a1.y, acc[5]);
            acc[6] = fmaf(wb, a1.z, acc[6]);  acc[7] = fmaf(wb, a1.w, acc[7]);
            acc[8] = fmaf(wb, a2.x, acc[8]);  acc[9] = fmaf(wb, a2.y, acc[9]);
            acc[10] = fmaf(wb, a2.z, acc[10]); acc[11] = fmaf(wb, a2.w, acc[11]);
            p += (size_t)SLICE * TP;
        }
    }

    const float I3 = rgb[i] * (1.0f / 3.0f);
    const float E = exp2f(-0.5f * LOG2E * I3 * I3);
    const float invf[NT] = {1.f, 1.f, 0.5f, 1.f / 6.f, 1.f / 24.f};
    float Pt[NT];
    Pt[0] = E;
#pragma unroll
    for (int k = 1; k < NT; ++k) Pt[k] = Pt[k - 1] * I3;

    // norm_b: compute in iter 0 (z-conv of tmpN), else read cached
    float inv_nb;
    if (it == 0) {
        float accN[NT] = {0.f, 0.f, 0.f, 0.f, 0.f};
        const float* pn = tmpN + (size_t)t * TP;
#pragma unroll 4
        for (int zp = 0; zp < DD; ++zp) {
            float wb = g160[iabs(z - zp)];
            float4 n0 = ((const float4*)pn)[0];
            float4 n1 = ((const float4*)pn)[1];
            accN[0] = fmaf(wb, n0.z, accN[0]);
            accN[1] = fmaf(wb, n0.w, accN[1]);
            accN[2] = fmaf(wb, n1.x, accN[2]);
            accN[3] = fmaf(wb, n1.y, accN[3]);
            accN[4] = fmaf(wb, n1.z, accN[4]);
            pn += (size_t)SLICE * TP;
        }
        float nb = 0.f;
#pragma unroll
        for (int k = 0; k < NT; ++k) nb = fmaf(Pt[k] * invf[k], accN[k], nb);
        normb[i] = nb;
        inv_nb = 1.0f / nb;
    } else {
        inv_nb = 1.0f / normb[i];
    }

    // spatial normalization (analytic, separable)
    float sx = 0.f, sy = 0.f, sz = 0.f;
#pragma unroll
    for (int xp = 0; xp < WW; ++xp) sx += g3[iabs(x - xp)];
#pragma unroll
    for (int yp = 0; yp < HH; ++yp) sy += g3[iabs(y - yp)];
#pragma unroll
    for (int zp = 0; zp < DD; ++zp) sz += g3[iabs(z - zp)];
    const float inv_ns = 1.0f / (sx * sy * sz);

    // mean-field update
    float s0 = acc[0] * inv_ns;
    float s1 = acc[1] * inv_ns;
    float b0 = 0.f, b1 = 0.f;
#pragma unroll
    for (int k = 0; k < NT; ++k) {
        float w = Pt[k] * invf[k];
        b0 = fmaf(w, acc[2 + 2 * k], b0);
        b1 = fmaf(w, acc[3 + 2 * k], b1);
    }
    b0 *= inv_nb;
    b1 *= inv_nb;
    float m0 = s0 * sw[0] + b0 * bw[0];
    float m1 = s1 * sw[1] + b1 * bw[1];
    float p0 = fmaf(compat[0], m0, compat[1] * m1);
    float p1 = fmaf(compat[2], m0, compat[3] * m1);
    const float2 uu = u2[i];
    float q0 = uu.x - p0;
    float q1 = uu.y - p1;

    if (it == 4) {
        out[i] = make_float2(q0, q1);
        return;
    }

    // xy-filter the new q for the next iteration
    float v[12], ov[12];
    v[0] = q0; v[1] = q1;
#pragma unroll
    for (int k = 0; k < NT; ++k) { v[2 + 2 * k] = Pt[k] * q0; v[3 + 2 * k] = Pt[k] * q1; }
    xy_conv12(sA, sB, g3, g160, y, x, v, ov);
    write12(tdst + (size_t)i * TP, ov);
}

extern "C" void kernel_launch(void* const* d_in, const int* in_sizes, int n_in,
                              void* d_out, int out_size, void* d_ws, size_t ws_size,
                              hipStream_t stream) {
    const float2* u2     = (const float2*)d_in[0];  // N*2
    const float*  rgb    = (const float*)d_in[1];   // N
    const float*  sw     = (const float*)d_in[2];
    const float*  bw     = (const float*)d_in[3];
    const float*  compat = (const float*)d_in[4];
    float2* out = (float2*)d_out;

    float* ws = (float*)d_ws;
    float* tmpA  = ws;                      // NPTS*TP
    float* tmpB  = ws + NPTS * TP;          // NPTS*TP
    float* tmpN  = ws + 2 * NPTS * TP;      // NPTS*TP
    float* normb = ws + 3 * NPTS * TP;      // NPTS

    crf_pre<<<DD, SLICE, 0, stream>>>(u2, rgb, tmpA, tmpN);

    const float* tsrc = tmpA;
    float* tdst = tmpB;
    for (int it = 0; it < 5; ++it) {
        crf_iter<<<DD, SLICE, 0, stream>>>(tsrc, tdst, tmpN, normb, rgb, u2,
                                           sw, bw, compat, out, it);
        const float* ns = tdst;
        tdst = (float*)tsrc;
        tsrc = ns;
    }
}